// Round 19
// baseline (426.860 us; speedup 1.0000x reference)
//
#include <hip/hip_runtime.h>
#include <hip/hip_bf16.h>

#define N_   8
#define P_   2048
#define K_   16
#define T1   8

typedef const float* fpp;
typedef __attribute__((ext_vector_type(8))) short short8;
typedef __attribute__((ext_vector_type(4))) short short4v;
typedef __attribute__((ext_vector_type(4))) float floatx4;

__device__ __forceinline__ float bcast(float v, int lane){
    return __uint_as_float(__builtin_amdgcn_readlane(__float_as_uint(v), (unsigned)lane));
}
__device__ __forceinline__ short f2bf(float f){
    unsigned u = __float_as_uint(f);
    unsigned r = (u + 0x7FFFu + ((u >> 16) & 1u)) >> 16;
    return (short)r;
}
__device__ __forceinline__ float bf2f(short s){
    return __uint_as_float(((unsigned)(unsigned short)s) << 16);
}
__device__ __forceinline__ float bf2fu(unsigned short s){
    return __uint_as_float(((unsigned)s) << 16);
}

// ==== FUSED FRONT: heterogeneous grid — 1024 knn blocks + 256 feat blocks,
//      interleaved 4:1 by dispatch index for CU co-residency (knn latency-bound,
//      feat VALU-bound: complementary pipes). knn body identical to R18. ====
__global__ __launch_bounds__(1024) void front_kernel(fpp points, fpp feat, fpp w0, fpp aw1,
        int* idxo, float* U, float* V, float* AU, float* AV){
    __shared__ float4 scand[2056];            // knn-only; feat path touches no LDS
    const int b = blockIdx.x;
    const int t = threadIdx.x;
    const int wave = t >> 6, lane = t & 63;
    if ((b % 5) < 4){
        // ---------------- KNN block ----------------
        const int kb = (b/5)*4 + (b%5);       // 0..1023
        const int n  = kb >> 7;
        const int p0 = (kb & 127) * 16;
        const int base = n << 11;
        for (int i = t; i < 2048; i += 1024){
            float x = points[(base+i)*3+0];
            float y = points[(base+i)*3+1];
            float z = points[(base+i)*3+2];
            scand[i + (i>>8)] = make_float4(x, y, z, x*x + y*y + z*z);
        }
        __syncthreads();
        const int pl = p0 + wave;
        const float4 me = scand[pl + (pl>>8)];
        const float px = me.x, py = me.y, pz = me.z, rp = me.w;
        float sd; int sq;
        {
            const float4 c = scand[lane];
            sd = (rp - 2.0f*(px*c.x + py*c.y + pz*c.z)) + c.w;
            sq = lane;
            #pragma unroll
            for (int k = 2; k <= 64; k <<= 1){
                #pragma unroll
                for (int j = k >> 1; j > 0; j >>= 1){
                    const float od = __shfl_xor(sd, j);
                    const int   oi = __shfl_xor(sq, j);
                    const bool takeSmaller = ((lane & k) == 0) == ((lane & j) == 0);
                    const bool otherLess   = (od < sd) || (od == sd && oi < sq);
                    const bool take = (takeSmaller == otherLess);
                    sd = take ? od : sd;
                    sq = take ? oi : sq;
                }
            }
        }
        for (int s = 1; s < 32; ++s){
            const int ci = s*64 + lane;
            const float4 c = scand[ci + (ci>>8)];
            const float d = (rp - 2.0f*(px*c.x + py*c.y + pz*c.z)) + c.w;
            const float thr = __shfl(sd, 16);
            unsigned long long mask = __ballot(d < thr);
            while (mask){
                const int src = __ffsll((long long)mask) - 1;
                mask &= mask - 1;
                const float dn = __shfl(d, src);
                const int   qn = __shfl(ci, src);
                float shd = __shfl_up(sd, 1);
                int   shq = __shfl_up(sq, 1);
                if (lane == 0) shd = -__builtin_inff();
                const bool c1 = shd > dn;
                const bool c2 = sd  > dn;
                sq = c1 ? shq : (c2 ? qn : sq);
                sd = c1 ? shd : (c2 ? dn : sd);
            }
        }
        if (lane >= 1 && lane <= 16)
            idxo[(base + pl)*K_ + (lane - 1)] = base + sq;
    } else {
        // ---------------- feat block: 4 row-groups x roles (U,V,A), 64 rows ----------------
        const int fb = b/5;                   // 0..255
        const int ro = wave & 3, g = wave >> 2;
        if (ro == 3) return;                  // idle wave (no barriers in this path)
        const int row0 = fb*64 + g*16;
        float wreg[64];
        if (ro == 0){
            #pragma unroll
            for (int c=0;c<64;c++) wreg[c] = w0[lane*128+c] - w0[lane*128+64+c];
        } else if (ro == 1){
            #pragma unroll
            for (int c=0;c<64;c++) wreg[c] = w0[lane*128+64+c];
        } else {
            if (lane < 32){
                #pragma unroll
                for (int c=0;c<64;c++) wreg[c] = aw1[lane*128+c] - aw1[lane*128+64+c];
            } else {
                const int o = lane - 32;
                #pragma unroll
                for (int c=0;c<64;c++) wreg[c] = aw1[o*128+64+c];
            }
        }
        for (int r=0;r<16;r++){
            const int row = row0 + r;
            const float fv = feat[row*64 + lane];
            float acc = 0.f;
            #pragma unroll
            for (int c=0;c<64;c++) acc = fmaf(bcast(fv, c), wreg[c], acc);
            if      (ro==0) U[row*64+lane]=acc;
            else if (ro==1) V[row*64+lane]=acc;
            else { if (lane<32) AU[row*32+lane]=acc; else AV[row*32+lane-32]=acc; }
        }
    }
}

// ------ SC stats (256 blocks x 64 rows) ------
__global__ __launch_bounds__(128) void sc_stats_kernel(fpp feat, fpp scw, float* scs, float* scq){
    __shared__ float swc[128*65];
    __shared__ float sf[64*64];
    const int t = threadIdx.x;
    for (int i=t;i<8192;i+=128) swc[(i>>6)*65+(i&63)] = scw[i];
    const int row0 = blockIdx.x*64;
    for (int i=t;i<4096;i+=128) sf[i] = feat[row0*64+i];
    __syncthreads();
    float psum=0.f, psq=0.f;
    for (int r=0;r<64;r++){
        float acc = 0.f;
        #pragma unroll
        for (int k=0;k<64;k++) acc = fmaf(sf[r*64+k], swc[t*65+k], acc);
        psum += acc; psq += acc*acc;
    }
    atomicAdd(&scs[t], psum);
    atomicAdd(&scq[t], psq);
}

// ------ attention + BN0 stats; AV rows pre-staged in per-wave LDS ------
__global__ __launch_bounds__(256) void attn_bn0_kernel(const int* idx, const float* U, const float* V,
        const float* AU, const float* AV, fpp b1, fpp w2, fpp b2, fpp tau,
        float* attw, float* bn0s, float* bn0q){
    __shared__ float sAV[4][16][36];
    const int t = threadIdx.x, w = t>>6, lane = t&63;
    const int pt0 = blockIdx.x*32 + w*8;
    const int kk = lane >> 2, h = lane & 3;
    float w2r[32];
    #pragma unroll
    for (int c=0;c<32;c++) w2r[c] = w2[h*32+c];
    const float b2v = b2[h];
    const float tv  = tau[0];
    float ssum=0.f, ssq=0.f;
    for (int j=0;j<8;j++){
        const int pt = pt0 + j;
        const int* ip = idx + pt*K_;
        {
            const int fl = lane >> 2, part = lane & 3;
            const int qf = ip[fl];
            const float4 a = *(const float4*)&AV[qf*32 + part*8];
            const float4 b = *(const float4*)&AV[qf*32 + part*8 + 4];
            *(float4*)&sAV[w][fl][part*8]     = a;
            *(float4*)&sAV[w][fl][part*8 + 4] = b;
        }
        __builtin_amdgcn_wave_barrier();
        const float uv = U[pt*64+lane];
        for (int k=0;k<K_;k++){
            const int q = ip[k];
            const float v = uv + V[q*64+lane];
            ssum += v; ssq += v*v;
        }
        float a2 = b2v;
        for (int c=0;c<32;c++){
            float a1 = AU[pt*32+c] + sAV[w][kk][c] + b1[c];
            a1 = a1 > 0.f ? a1 : 0.2f*a1;
            a2 = fmaf(a1, w2r[c], a2);
        }
        const float lt = a2 / tv;
        float m = lt;
        m = fmaxf(m, __shfl_xor(m, 4));  m = fmaxf(m, __shfl_xor(m, 8));
        m = fmaxf(m, __shfl_xor(m, 16)); m = fmaxf(m, __shfl_xor(m, 32));
        const float e = expf(lt - m);
        float s = e;
        s += __shfl_xor(s, 4);  s += __shfl_xor(s, 8);
        s += __shfl_xor(s, 16); s += __shfl_xor(s, 32);
        attw[pt*64 + lane] = e / s;
        __builtin_amdgcn_wave_barrier();
    }
    __shared__ float rs[256], rq[256];
    rs[t]=ssum; rq[t]=ssq; __syncthreads();
    if (t < 64){
        atomicAdd(&bn0s[t], rs[t]+rs[t+64]+rs[t+128]+rs[t+192]);
        atomicAdd(&bn0q[t], rq[t]+rq[t+64]+rq[t+128]+rq[t+192]);
    }
}

// ------ fold BN into per-channel scale/shift ------
__global__ __launch_bounds__(128) void bn_finalize_kernel(const float* s, const float* q, fpp g, fpp b,
        float inv_cnt, int C, float* scale, float* shift){
    const int c = threadIdx.x;
    if (c < C){
        const float mu  = s[c]*inv_cnt;
        const float var = fmaxf(q[c]*inv_cnt - mu*mu, 0.f);
        const float sc  = g[c] * rsqrtf(var + 1e-5f);
        scale[c]=sc; shift[c] = b[c] - mu*sc;
    }
}

// ------ merged BN0 + SC finalize ------
__global__ __launch_bounds__(192) void bn_finalize2_kernel(const float* s0, const float* q0,
        fpp g0, fpp b0, const float* ss, const float* qs, fpp gs, fpp bs,
        float* sc0, float* sh0, float* scsc, float* shsc){
    const int c = threadIdx.x;
    if (c < 64){
        const float mu  = s0[c]*(1.0f/262144.0f);
        const float var = fmaxf(q0[c]*(1.0f/262144.0f) - mu*mu, 0.f);
        const float sc  = g0[c] * rsqrtf(var + 1e-5f);
        sc0[c]=sc; sh0[c]=b0[c]-mu*sc;
    } else {
        const int cc = c - 64;
        const float mu  = ss[cc]*(1.0f/16384.0f);
        const float var = fmaxf(qs[cc]*(1.0f/16384.0f) - mu*mu, 0.f);
        const float sc  = gs[cc] * rsqrtf(var + 1e-5f);
        scsc[cc]=sc; shsc[cc]=bs[cc]-mu*sc;
    }
}

// ====== MFMA conv1: gather + conv1 + Y1 store (bf16) + BN1 stats ======
__global__ __launch_bounds__(256) void mfma_conv1_kernel(const int* idx, const float* U, const float* V,
        fpp w1, const float* sc0, const float* sh0, float* bn1s, float* bn1q,
        unsigned short* y1out){
    __shared__ __align__(16) short WH[64*72], WL[64*72];
    __shared__ __align__(16) short AH[64*72], AL[64*72];
    __shared__ float ssum[64], ssq[64];
    const int t = threadIdx.x, lane = t & 63, w = t >> 6;
    const int L = lane & 15, Q = lane >> 4;
    for (int i = t; i < 4096; i += 256){
        const float wv = w1[i];
        const short hh = f2bf(wv);
        const int n = i >> 6, k = i & 63;
        WH[n*72+k] = hh;
        WL[n*72+k] = f2bf(wv - bf2f(hh));
    }
    if (t < 64){ ssum[t]=0.f; ssq[t]=0.f; }
    __syncthreads();
    short8 bh[4][2], bl[4][2];
    #pragma unroll
    for (int nt=0; nt<4; ++nt){
        #pragma unroll
        for (int ks=0; ks<2; ++ks){
            const int off = (nt*16+L)*72 + ks*32 + Q*8;
            bh[nt][ks] = *(const short8*)&WH[off];
            bl[nt][ks] = *(const short8*)&WL[off];
        }
    }
    const int m0 = w*16;
    const int r = t >> 2, cq = t & 3;
    float sacc[4] = {0,0,0,0}, qacc[4] = {0,0,0,0};
    for (int tile = 0; tile < T1; ++tile){
        __syncthreads();
        const int e0 = (blockIdx.x*T1 + tile) * 64;
        {
            const int s = e0 + r;
            const int p = s >> 4, q = idx[s];
            const float4* up = (const float4*)&U[p*64 + cq*16];
            const float4* vq = (const float4*)&V[q*64 + cq*16];
            #pragma unroll
            for (int b4=0; b4<4; ++b4){
                const float4 uv4 = up[b4];
                const float4 vv4 = vq[b4];
                const int c0 = cq*16 + b4*4;
                float av[4] = {uv4.x+vv4.x, uv4.y+vv4.y, uv4.z+vv4.z, uv4.w+vv4.w};
                short4v h4, l4;
                #pragma unroll
                for (int j=0;j<4;j++){
                    const int c = c0 + j;
                    const float a0 = fmaxf(fmaf(av[j], sc0[c], sh0[c]), 0.f);
                    const short hh = f2bf(a0);
                    h4[j] = hh;
                    l4[j] = f2bf(a0 - bf2f(hh));
                }
                *(short4v*)&AH[r*72 + c0] = h4;
                *(short4v*)&AL[r*72 + c0] = l4;
            }
        }
        __syncthreads();
        floatx4 acc[4];
        #pragma unroll
        for (int nt=0;nt<4;nt++) acc[nt] = (floatx4){0.f,0.f,0.f,0.f};
        #pragma unroll
        for (int ks=0; ks<2; ++ks){
            const int aoff = (m0 + L)*72 + ks*32 + Q*8;
            const short8 ah = *(const short8*)&AH[aoff];
            const short8 al = *(const short8*)&AL[aoff];
            #pragma unroll
            for (int nt=0;nt<4;nt++){
                acc[nt] = __builtin_amdgcn_mfma_f32_16x16x32_bf16(ah, bh[nt][ks], acc[nt], 0,0,0);
                acc[nt] = __builtin_amdgcn_mfma_f32_16x16x32_bf16(ah, bl[nt][ks], acc[nt], 0,0,0);
                acc[nt] = __builtin_amdgcn_mfma_f32_16x16x32_bf16(al, bh[nt][ks], acc[nt], 0,0,0);
            }
        }
        #pragma unroll
        for (int nt=0;nt<4;nt++){
            const int o = nt*16 + L;
            #pragma unroll
            for (int rr=0;rr<4;rr++){
                const float v = acc[nt][rr];
                y1out[(e0 + m0 + Q*4 + rr)*64 + o] = (unsigned short)f2bf(v);
                sacc[nt]+=v; qacc[nt]+=v*v;
            }
        }
    }
    #pragma unroll
    for (int nt=0;nt<4;nt++){
        atomicAdd(&ssum[nt*16+L], sacc[nt]);
        atomicAdd(&ssq [nt*16+L], qacc[nt]);
    }
    __syncthreads();
    if (t < 64){
        atomicAdd(&bn1s[t], ssum[t]);
        atomicAdd(&bn1q[t], ssq[t]);
    }
}

// ====== MFMA conv2 v3: read Y1 -> Y2 + BN2 stats ======
__global__ __launch_bounds__(256) void mfma_conv2_kernel(const unsigned short* y1in,
        fpp w2, const float* sc1, const float* sh1,
        float* bn2s, float* bn2q, unsigned short* y2out){
    __shared__ __align__(16) short WH2[128*72], WL2[128*72];
    __shared__ __align__(16) short AH[64*72], AL[64*72];
    __shared__ float ssum[128], ssq[128];
    const int t = threadIdx.x, lane = t & 63, w = t >> 6;
    const int L = lane & 15, Q = lane >> 4;
    for (int i = t; i < 8192; i += 256){
        const float wv = w2[i];
        const short hh = f2bf(wv);
        WH2[(i>>6)*72+(i&63)] = hh;
        WL2[(i>>6)*72+(i&63)] = f2bf(wv - bf2f(hh));
    }
    if (t < 128){ ssum[t]=0.f; ssq[t]=0.f; }
    const int m0 = w*16;
    const int r = t >> 2, cq = t & 3;
    float s1r[16], h1r[16];
    #pragma unroll
    for (int j=0;j<16;j++){ s1r[j] = sc1[cq*16+j]; h1r[j] = sh1[cq*16+j]; }
    float sacc[8] = {0,0,0,0,0,0,0,0}, qacc[8] = {0,0,0,0,0,0,0,0};
    for (int tile = 0; tile < T1; ++tile){
        __syncthreads();
        const int e0 = (blockIdx.x*T1 + tile) * 64;
        {
            const short8 y8a = *(const short8*)&y1in[(e0 + r)*64 + cq*16];
            const short8 y8b = *(const short8*)&y1in[(e0 + r)*64 + cq*16 + 8];
            short4v h4, l4;
            #pragma unroll
            for (int half=0; half<2; ++half){
                const short8 y8 = half ? y8b : y8a;
                #pragma unroll
                for (int g=0; g<2; ++g){
                    #pragma unroll
                    for (int j=0;j<4;j++){
                        const int jj = g*4 + j;
                        const float a1 = fmaxf(fmaf(bf2fu((unsigned short)y8[jj]),
                                                    s1r[half*8+jj], h1r[half*8+jj]), 0.f);
                        const short hh = f2bf(a1);
                        h4[j] = hh;
                        l4[j] = f2bf(a1 - bf2f(hh));
                    }
                    const int c0 = cq*16 + half*8 + g*4;
                    *(short4v*)&AH[r*72 + c0] = h4;
                    *(short4v*)&AL[r*72 + c0] = l4;
                }
            }
        }
        __syncthreads();
        floatx4 acc2[8];
        #pragma unroll
        for (int nt=0;nt<8;nt++) acc2[nt] = (floatx4){0.f,0.f,0.f,0.f};
        #pragma unroll
        for (int ks=0; ks<2; ++ks){
            const int aoff = (m0 + L)*72 + ks*32 + Q*8;
            const short8 ah = *(const short8*)&AH[aoff];
            const short8 al = *(const short8*)&AL[aoff];
            #pragma unroll
            for (int nt=0;nt<8;nt++){
                const int boff = (nt*16+L)*72 + ks*32 + Q*8;
                const short8 wh = *(const short8*)&WH2[boff];
                const short8 wl = *(const short8*)&WL2[boff];
                acc2[nt] = __builtin_amdgcn_mfma_f32_16x16x32_bf16(ah, wh, acc2[nt], 0,0,0);
                acc2[nt] = __builtin_amdgcn_mfma_f32_16x16x32_bf16(ah, wl, acc2[nt], 0,0,0);
                acc2[nt] = __builtin_amdgcn_mfma_f32_16x16x32_bf16(al, wh, acc2[nt], 0,0,0);
            }
        }
        #pragma unroll
        for (int nt=0;nt<8;nt++){
            const int o = nt*16 + L;
            #pragma unroll
            for (int rr=0;rr<4;rr++){
                const float v = acc2[nt][rr];
                const int s = e0 + m0 + Q*4 + rr;
                y2out[s*128 + o] = (unsigned short)f2bf(v);
                sacc[nt] += v; qacc[nt] += v*v;
            }
        }
    }
    #pragma unroll
    for (int nt=0;nt<8;nt++){
        atomicAdd(&ssum[nt*16+L], sacc[nt]);
        atomicAdd(&ssq [nt*16+L], qacc[nt]);
    }
    __syncthreads();
    if (t < 128){
        atomicAdd(&bn2s[t], ssum[t]);
        atomicAdd(&bn2q[t], ssq[t]);
    }
}

// ------ combine (read bf16 Y2) ------
__global__ __launch_bounds__(256) void combine_fast_kernel(const unsigned short* y2, const float* attw,
        const float* sc2, const float* sh2, float* xcomb, float* msum){
    __shared__ float rs[512];
    const int t=threadIdx.x, w=t>>6, lane=t&63;
    const float s2a=sc2[lane], h2a=sh2[lane], s2b=sc2[64+lane], h2b=sh2[64+lane];
    const int pt0 = blockIdx.x*16 + w*4;
    const int hsel = lane >> 5;
    float m0=0.f, m1=0.f;
    for (int j=0;j<4;j++){
        const int pt = pt0 + j;
        float acc0=0.f, acc1=0.f;
        for (int k=0;k<K_;k++){
            const int s = pt*K_ + k;
            const float r0 = fmaxf(fmaf(bf2fu(y2[s*128+lane]),    s2a, h2a), 0.f);
            const float r1 = fmaxf(fmaf(bf2fu(y2[s*128+64+lane]), s2b, h2b), 0.f);
            acc0 = fmaf(r0, attw[s*4 + hsel],     acc0);
            acc1 = fmaf(r1, attw[s*4 + 2 + hsel], acc1);
        }
        xcomb[pt*128+lane]    = acc0;
        xcomb[pt*128+64+lane] = acc1;
        m0 += acc0; m1 += acc1;
    }
    rs[t]=m0; rs[256+t]=m1; __syncthreads();
    if (t<64){
        const int n = (blockIdx.x*16) >> 11;
        atomicAdd(&msum[n*128+t],    rs[t]+rs[t+64]+rs[t+128]+rs[t+192]);
        atomicAdd(&msum[n*128+64+t], rs[256+t]+rs[256+t+64]+rs[256+t+128]+rs[256+t+192]);
    }
}

// ------ SE gate ------
__global__ __launch_bounds__(128) void se_kernel(const float* msum, fpp w1se, fpp w2se, float* sev){
    __shared__ float tl[32];
    const int t = threadIdx.x;
    for (int n=0;n<N_;n++){
        if (t < 32){
            float acc=0.f;
            for (int c=0;c<128;c++) acc = fmaf(msum[n*128+c]*(1.f/2048.f), w1se[t*128+c], acc);
            tl[t] = fmaxf(acc, 0.f);
        }
        __syncthreads();
        float acc=0.f;
        for (int hh=0;hh<32;hh++) acc = fmaf(tl[hh], w2se[t*32+hh], acc);
        sev[n*128+t] = 1.f/(1.f+expf(-acc));
        __syncthreads();
    }
}

// ------ final: 256 blocks x 64 rows ------
__global__ __launch_bounds__(128) void final_kernel(fpp feat, fpp scw, const float* xcomb,
        const float* sev, const float* scsc, const float* shsc, float* out){
    __shared__ float swc[128*65];
    __shared__ float sf[64*64];
    const int t = threadIdx.x;
    for (int i=t;i<8192;i+=128) swc[(i>>6)*65+(i&63)] = scw[i];
    const int row0 = blockIdx.x*64;
    for (int i=t;i<4096;i+=128) sf[i] = feat[row0*64+i];
    __syncthreads();
    const int c = t;
    const float scl = scsc[c], shf = shsc[c];
    for (int r=0;r<64;r++){
        const int row = row0 + r;
        float acc = 0.f;
        #pragma unroll
        for (int k=0;k<64;k++) acc = fmaf(sf[r*64+k], swc[c*65+k], acc);
        const int n = row >> 11;
        out[row*128+c] = xcomb[row*128+c]*sev[n*128+c] + fmaxf(fmaf(acc, scl, shf), 0.f);
    }
}

extern "C" void kernel_launch(void* const* d_in, const int* in_sizes, int n_in,
                              void* d_out, int out_size, void* d_ws, size_t ws_size,
                              hipStream_t stream) {
    fpp points  = (fpp)d_in[0];
    fpp feat    = (fpp)d_in[1];
    fpp conv_w0 = (fpp)d_in[2];
    fpp conv_w1 = (fpp)d_in[3];
    fpp conv_w2 = (fpp)d_in[4];
    fpp bn_g0 = (fpp)d_in[5],  bn_b0 = (fpp)d_in[6];
    fpp bn_g1 = (fpp)d_in[7],  bn_b1 = (fpp)d_in[8];
    fpp bn_g2 = (fpp)d_in[9],  bn_b2 = (fpp)d_in[10];
    fpp attn_w1 = (fpp)d_in[11], attn_b1 = (fpp)d_in[12];
    fpp attn_w2 = (fpp)d_in[13], attn_b2 = (fpp)d_in[14];
    fpp tau  = (fpp)d_in[15];
    fpp sc_w = (fpp)d_in[16], sc_g = (fpp)d_in[17], sc_b = (fpp)d_in[18];
    fpp se_w1 = (fpp)d_in[19], se_w2 = (fpp)d_in[20];

    float* W = (float*)d_ws;
    float* BN0S=W+0;    float* BN0Q=W+64;
    float* BN1S=W+128;  float* BN1Q=W+192;
    float* BN2S=W+256;  float* BN2Q=W+384;
    float* SCS =W+512;  float* SCQ =W+640;
    float* SC0 =W+768;  float* SH0 =W+832;
    float* SC1 =W+896;  float* SH1 =W+960;
    float* SC2 =W+1024; float* SH2 =W+1152;
    float* SCSC=W+1280; float* SHSC=W+1408;
    float* MSUM=W+1536; float* SEV =W+2560;
    int*   IDX  = (int*)(W + 4096);
    float* U    = W + 266240;
    float* V    = U + 1048576;
    float* AU   = V + 1048576;
    float* AV   = AU + 524288;
    float* ATTW = AV + 524288;
    float* XCOMB= ATTW + 1048576;                          // ends 6,557,696 floats
    unsigned short* Y2 = (unsigned short*)(W + 6557696);   // 33,554,432 ushort
    unsigned short* Y1 = Y2 + 33554432;                    // 16,777,216 ushort

    hipMemsetAsync(d_ws, 0, 4096*sizeof(float), stream);

    front_kernel<<<1280, 1024, 0, stream>>>(points, feat, conv_w0, attn_w1,
                                            IDX, U, V, AU, AV);
    sc_stats_kernel<<<256, 128, 0, stream>>>(feat, sc_w, SCS, SCQ);
    attn_bn0_kernel<<<512, 256, 0, stream>>>(IDX, U, V, AU, AV,
                                             attn_b1, attn_w2, attn_b2, tau,
                                             ATTW, BN0S, BN0Q);
    bn_finalize2_kernel<<<1, 192, 0, stream>>>(BN0S, BN0Q, bn_g0, bn_b0,
                                               SCS, SCQ, sc_g, sc_b,
                                               SC0, SH0, SCSC, SHSC);
    mfma_conv1_kernel<<<512, 256, 0, stream>>>(IDX, U, V, conv_w1, SC0, SH0,
                                               BN1S, BN1Q, Y1);
    bn_finalize_kernel<<<1, 128, 0, stream>>>(BN1S, BN1Q, bn_g1, bn_b1,
                                              1.0f/262144.0f, 64, SC1, SH1);
    mfma_conv2_kernel<<<512, 256, 0, stream>>>(Y1, conv_w2, SC1, SH1,
                                               BN2S, BN2Q, Y2);
    bn_finalize_kernel<<<1, 128, 0, stream>>>(BN2S, BN2Q, bn_g2, bn_b2,
                                              1.0f/262144.0f, 128, SC2, SH2);
    combine_fast_kernel<<<1024, 256, 0, stream>>>(Y2, ATTW, SC2, SH2, XCOMB, MSUM);
    se_kernel<<<1, 128, 0, stream>>>(MSUM, se_w1, se_w2, SEV);
    final_kernel<<<256, 128, 0, stream>>>(feat, sc_w, XCOMB, SEV, SCSC, SHSC,
                                          (float*)d_out);
}

// Round 20
// 416.005 us; speedup vs baseline: 1.0261x; 1.0261x over previous
//
#include <hip/hip_runtime.h>
#include <hip/hip_bf16.h>

#define N_   8
#define P_   2048
#define K_   16
#define T1   8

typedef const float* fpp;
typedef __attribute__((ext_vector_type(8))) short short8;
typedef __attribute__((ext_vector_type(4))) short short4v;
typedef __attribute__((ext_vector_type(4))) float floatx4;

__device__ __forceinline__ float bcast(float v, int lane){
    return __uint_as_float(__builtin_amdgcn_readlane(__float_as_uint(v), (unsigned)lane));
}
__device__ __forceinline__ short f2bf(float f){
    unsigned u = __float_as_uint(f);
    unsigned r = (u + 0x7FFFu + ((u >> 16) & 1u)) >> 16;
    return (short)r;
}
__device__ __forceinline__ float bf2f(short s){
    return __uint_as_float(((unsigned)(unsigned short)s) << 16);
}
__device__ __forceinline__ float bf2fu(unsigned short s){
    return __uint_as_float(((unsigned)s) << 16);
}

// ---- KNN v5: wave-per-point, 512-thread blocks (8 waves) for full wave-slot packing.
//      Per-point math identical to v4 (bitonic init + ballot-gated inserts). ----
__global__ __launch_bounds__(512) void knn_kernel(fpp points, int* idxo){
    __shared__ float4 scand[2056];            // pos(i) = i + (i>>8)
    const int t = threadIdx.x;
    const int wave = t >> 6, lane = t & 63;
    const int n  = blockIdx.x >> 8;           // 256 blocks per batch
    const int p0 = (blockIdx.x & 255) * 8;
    const int base = n << 11;
    for (int i = t; i < 2048; i += 512){
        float x = points[(base+i)*3+0];
        float y = points[(base+i)*3+1];
        float z = points[(base+i)*3+2];
        scand[i + (i>>8)] = make_float4(x, y, z, x*x + y*y + z*z);
    }
    __syncthreads();
    const int pl = p0 + wave;
    const float4 me = scand[pl + (pl>>8)];
    const float px = me.x, py = me.y, pz = me.z, rp = me.w;
    float sd; int sq;
    {
        const float4 c = scand[lane];
        sd = (rp - 2.0f*(px*c.x + py*c.y + pz*c.z)) + c.w;
        sq = lane;
        #pragma unroll
        for (int k = 2; k <= 64; k <<= 1){
            #pragma unroll
            for (int j = k >> 1; j > 0; j >>= 1){
                const float od = __shfl_xor(sd, j);
                const int   oi = __shfl_xor(sq, j);
                const bool takeSmaller = ((lane & k) == 0) == ((lane & j) == 0);
                const bool otherLess   = (od < sd) || (od == sd && oi < sq);
                const bool take = (takeSmaller == otherLess);
                sd = take ? od : sd;
                sq = take ? oi : sq;
            }
        }
    }
    for (int s = 1; s < 32; ++s){
        const int ci = s*64 + lane;
        const float4 c = scand[ci + (ci>>8)];
        const float d = (rp - 2.0f*(px*c.x + py*c.y + pz*c.z)) + c.w;
        const float thr = __shfl(sd, 16);
        unsigned long long mask = __ballot(d < thr);
        while (mask){
            const int src = __ffsll((long long)mask) - 1;
            mask &= mask - 1;
            const float dn = __shfl(d, src);
            const int   qn = __shfl(ci, src);
            float shd = __shfl_up(sd, 1);
            int   shq = __shfl_up(sq, 1);
            if (lane == 0) shd = -__builtin_inff();
            const bool c1 = shd > dn;
            const bool c2 = sd  > dn;
            sq = c1 ? shq : (c2 ? qn : sq);
            sd = c1 ? shd : (c2 ? dn : sd);
        }
    }
    if (lane >= 1 && lane <= 16)
        idxo[(base + pl)*K_ + (lane - 1)] = base + sq;
}

// ------ per-point transforms: U,V (conv0 split), AU,AV (attn1 split) ------
__global__ __launch_bounds__(192) void feat_gemm_kernel(fpp feat, fpp w0, fpp aw1,
        float* U, float* V, float* AU, float* AV){
    const int t = threadIdx.x;
    const int w = t >> 6, lane = t & 63;
    const int row0 = blockIdx.x * 16;
    float wreg[64];
    if (w == 0){
        #pragma unroll
        for (int c=0;c<64;c++) wreg[c] = w0[lane*128+c] - w0[lane*128+64+c];
    } else if (w == 1){
        #pragma unroll
        for (int c=0;c<64;c++) wreg[c] = w0[lane*128+64+c];
    } else {
        if (lane < 32){
            #pragma unroll
            for (int c=0;c<64;c++) wreg[c] = aw1[lane*128+c] - aw1[lane*128+64+c];
        } else {
            const int o = lane - 32;
            #pragma unroll
            for (int c=0;c<64;c++) wreg[c] = aw1[o*128+64+c];
        }
    }
    for (int r=0;r<16;r++){
        const int row = row0 + r;
        const float fv = feat[row*64 + lane];
        float acc = 0.f;
        #pragma unroll
        for (int c=0;c<64;c++) acc = fmaf(bcast(fv, c), wreg[c], acc);
        if      (w==0) U[row*64+lane]=acc;
        else if (w==1) V[row*64+lane]=acc;
        else { if (lane<32) AU[row*32+lane]=acc; else AV[row*32+lane-32]=acc; }
    }
}

// ------ SC stats (256 blocks x 64 rows) ------
__global__ __launch_bounds__(128) void sc_stats_kernel(fpp feat, fpp scw, float* scs, float* scq){
    __shared__ float swc[128*65];
    __shared__ float sf[64*64];
    const int t = threadIdx.x;
    for (int i=t;i<8192;i+=128) swc[(i>>6)*65+(i&63)] = scw[i];
    const int row0 = blockIdx.x*64;
    for (int i=t;i<4096;i+=128) sf[i] = feat[row0*64+i];
    __syncthreads();
    float psum=0.f, psq=0.f;
    for (int r=0;r<64;r++){
        float acc = 0.f;
        #pragma unroll
        for (int k=0;k<64;k++) acc = fmaf(sf[r*64+k], swc[t*65+k], acc);
        psum += acc; psq += acc*acc;
    }
    atomicAdd(&scs[t], psum);
    atomicAdd(&scq[t], psq);
}

// ------ attention + BN0 stats; AV rows pre-staged in per-wave LDS ------
__global__ __launch_bounds__(256) void attn_bn0_kernel(const int* idx, const float* U, const float* V,
        const float* AU, const float* AV, fpp b1, fpp w2, fpp b2, fpp tau,
        float* attw, float* bn0s, float* bn0q){
    __shared__ float sAV[4][16][36];
    const int t = threadIdx.x, w = t>>6, lane = t&63;
    const int pt0 = blockIdx.x*32 + w*8;
    const int kk = lane >> 2, h = lane & 3;
    float w2r[32];
    #pragma unroll
    for (int c=0;c<32;c++) w2r[c] = w2[h*32+c];
    const float b2v = b2[h];
    const float tv  = tau[0];
    float ssum=0.f, ssq=0.f;
    for (int j=0;j<8;j++){
        const int pt = pt0 + j;
        const int* ip = idx + pt*K_;
        {
            const int fl = lane >> 2, part = lane & 3;
            const int qf = ip[fl];
            const float4 a = *(const float4*)&AV[qf*32 + part*8];
            const float4 b = *(const float4*)&AV[qf*32 + part*8 + 4];
            *(float4*)&sAV[w][fl][part*8]     = a;
            *(float4*)&sAV[w][fl][part*8 + 4] = b;
        }
        __builtin_amdgcn_wave_barrier();
        const float uv = U[pt*64+lane];
        for (int k=0;k<K_;k++){
            const int q = ip[k];
            const float v = uv + V[q*64+lane];
            ssum += v; ssq += v*v;
        }
        float a2 = b2v;
        for (int c=0;c<32;c++){
            float a1 = AU[pt*32+c] + sAV[w][kk][c] + b1[c];
            a1 = a1 > 0.f ? a1 : 0.2f*a1;
            a2 = fmaf(a1, w2r[c], a2);
        }
        const float lt = a2 / tv;
        float m = lt;
        m = fmaxf(m, __shfl_xor(m, 4));  m = fmaxf(m, __shfl_xor(m, 8));
        m = fmaxf(m, __shfl_xor(m, 16)); m = fmaxf(m, __shfl_xor(m, 32));
        const float e = expf(lt - m);
        float s = e;
        s += __shfl_xor(s, 4);  s += __shfl_xor(s, 8);
        s += __shfl_xor(s, 16); s += __shfl_xor(s, 32);
        attw[pt*64 + lane] = e / s;
        __builtin_amdgcn_wave_barrier();
    }
    __shared__ float rs[256], rq[256];
    rs[t]=ssum; rq[t]=ssq; __syncthreads();
    if (t < 64){
        atomicAdd(&bn0s[t], rs[t]+rs[t+64]+rs[t+128]+rs[t+192]);
        atomicAdd(&bn0q[t], rq[t]+rq[t+64]+rq[t+128]+rq[t+192]);
    }
}

// ------ fold BN into per-channel scale/shift ------
__global__ __launch_bounds__(128) void bn_finalize_kernel(const float* s, const float* q, fpp g, fpp b,
        float inv_cnt, int C, float* scale, float* shift){
    const int c = threadIdx.x;
    if (c < C){
        const float mu  = s[c]*inv_cnt;
        const float var = fmaxf(q[c]*inv_cnt - mu*mu, 0.f);
        const float sc  = g[c] * rsqrtf(var + 1e-5f);
        scale[c]=sc; shift[c] = b[c] - mu*sc;
    }
}

// ------ merged BN0 + SC finalize ------
__global__ __launch_bounds__(192) void bn_finalize2_kernel(const float* s0, const float* q0,
        fpp g0, fpp b0, const float* ss, const float* qs, fpp gs, fpp bs,
        float* sc0, float* sh0, float* scsc, float* shsc){
    const int c = threadIdx.x;
    if (c < 64){
        const float mu  = s0[c]*(1.0f/262144.0f);
        const float var = fmaxf(q0[c]*(1.0f/262144.0f) - mu*mu, 0.f);
        const float sc  = g0[c] * rsqrtf(var + 1e-5f);
        sc0[c]=sc; sh0[c]=b0[c]-mu*sc;
    } else {
        const int cc = c - 64;
        const float mu  = ss[cc]*(1.0f/16384.0f);
        const float var = fmaxf(qs[cc]*(1.0f/16384.0f) - mu*mu, 0.f);
        const float sc  = gs[cc] * rsqrtf(var + 1e-5f);
        scsc[cc]=sc; shsc[cc]=bs[cc]-mu*sc;
    }
}

// ====== MFMA conv1: gather + conv1 + Y1 store (bf16) + BN1 stats ======
__global__ __launch_bounds__(256) void mfma_conv1_kernel(const int* idx, const float* U, const float* V,
        fpp w1, const float* sc0, const float* sh0, float* bn1s, float* bn1q,
        unsigned short* y1out){
    __shared__ __align__(16) short WH[64*72], WL[64*72];
    __shared__ __align__(16) short AH[64*72], AL[64*72];
    __shared__ float ssum[64], ssq[64];
    const int t = threadIdx.x, lane = t & 63, w = t >> 6;
    const int L = lane & 15, Q = lane >> 4;
    for (int i = t; i < 4096; i += 256){
        const float wv = w1[i];
        const short hh = f2bf(wv);
        const int n = i >> 6, k = i & 63;
        WH[n*72+k] = hh;
        WL[n*72+k] = f2bf(wv - bf2f(hh));
    }
    if (t < 64){ ssum[t]=0.f; ssq[t]=0.f; }
    __syncthreads();
    short8 bh[4][2], bl[4][2];
    #pragma unroll
    for (int nt=0; nt<4; ++nt){
        #pragma unroll
        for (int ks=0; ks<2; ++ks){
            const int off = (nt*16+L)*72 + ks*32 + Q*8;
            bh[nt][ks] = *(const short8*)&WH[off];
            bl[nt][ks] = *(const short8*)&WL[off];
        }
    }
    const int m0 = w*16;
    const int r = t >> 2, cq = t & 3;
    float sacc[4] = {0,0,0,0}, qacc[4] = {0,0,0,0};
    for (int tile = 0; tile < T1; ++tile){
        __syncthreads();
        const int e0 = (blockIdx.x*T1 + tile) * 64;
        {
            const int s = e0 + r;
            const int p = s >> 4, q = idx[s];
            const float4* up = (const float4*)&U[p*64 + cq*16];
            const float4* vq = (const float4*)&V[q*64 + cq*16];
            #pragma unroll
            for (int b4=0; b4<4; ++b4){
                const float4 uv4 = up[b4];
                const float4 vv4 = vq[b4];
                const int c0 = cq*16 + b4*4;
                float av[4] = {uv4.x+vv4.x, uv4.y+vv4.y, uv4.z+vv4.z, uv4.w+vv4.w};
                short4v h4, l4;
                #pragma unroll
                for (int j=0;j<4;j++){
                    const int c = c0 + j;
                    const float a0 = fmaxf(fmaf(av[j], sc0[c], sh0[c]), 0.f);
                    const short hh = f2bf(a0);
                    h4[j] = hh;
                    l4[j] = f2bf(a0 - bf2f(hh));
                }
                *(short4v*)&AH[r*72 + c0] = h4;
                *(short4v*)&AL[r*72 + c0] = l4;
            }
        }
        __syncthreads();
        floatx4 acc[4];
        #pragma unroll
        for (int nt=0;nt<4;nt++) acc[nt] = (floatx4){0.f,0.f,0.f,0.f};
        #pragma unroll
        for (int ks=0; ks<2; ++ks){
            const int aoff = (m0 + L)*72 + ks*32 + Q*8;
            const short8 ah = *(const short8*)&AH[aoff];
            const short8 al = *(const short8*)&AL[aoff];
            #pragma unroll
            for (int nt=0;nt<4;nt++){
                acc[nt] = __builtin_amdgcn_mfma_f32_16x16x32_bf16(ah, bh[nt][ks], acc[nt], 0,0,0);
                acc[nt] = __builtin_amdgcn_mfma_f32_16x16x32_bf16(ah, bl[nt][ks], acc[nt], 0,0,0);
                acc[nt] = __builtin_amdgcn_mfma_f32_16x16x32_bf16(al, bh[nt][ks], acc[nt], 0,0,0);
            }
        }
        #pragma unroll
        for (int nt=0;nt<4;nt++){
            const int o = nt*16 + L;
            #pragma unroll
            for (int rr=0;rr<4;rr++){
                const float v = acc[nt][rr];
                y1out[(e0 + m0 + Q*4 + rr)*64 + o] = (unsigned short)f2bf(v);
                sacc[nt]+=v; qacc[nt]+=v*v;
            }
        }
    }
    #pragma unroll
    for (int nt=0;nt<4;nt++){
        atomicAdd(&ssum[nt*16+L], sacc[nt]);
        atomicAdd(&ssq [nt*16+L], qacc[nt]);
    }
    __syncthreads();
    if (t < 64){
        atomicAdd(&bn1s[t], ssum[t]);
        atomicAdd(&bn1q[t], ssq[t]);
    }
}

// ====== MFMA conv2 v3: read Y1 -> Y2 + BN2 stats ======
__global__ __launch_bounds__(256) void mfma_conv2_kernel(const unsigned short* y1in,
        fpp w2, const float* sc1, const float* sh1,
        float* bn2s, float* bn2q, unsigned short* y2out){
    __shared__ __align__(16) short WH2[128*72], WL2[128*72];
    __shared__ __align__(16) short AH[64*72], AL[64*72];
    __shared__ float ssum[128], ssq[128];
    const int t = threadIdx.x, lane = t & 63, w = t >> 6;
    const int L = lane & 15, Q = lane >> 4;
    for (int i = t; i < 8192; i += 256){
        const float wv = w2[i];
        const short hh = f2bf(wv);
        WH2[(i>>6)*72+(i&63)] = hh;
        WL2[(i>>6)*72+(i&63)] = f2bf(wv - bf2f(hh));
    }
    if (t < 128){ ssum[t]=0.f; ssq[t]=0.f; }
    const int m0 = w*16;
    const int r = t >> 2, cq = t & 3;
    float s1r[16], h1r[16];
    #pragma unroll
    for (int j=0;j<16;j++){ s1r[j] = sc1[cq*16+j]; h1r[j] = sh1[cq*16+j]; }
    float sacc[8] = {0,0,0,0,0,0,0,0}, qacc[8] = {0,0,0,0,0,0,0,0};
    for (int tile = 0; tile < T1; ++tile){
        __syncthreads();
        const int e0 = (blockIdx.x*T1 + tile) * 64;
        {
            const short8 y8a = *(const short8*)&y1in[(e0 + r)*64 + cq*16];
            const short8 y8b = *(const short8*)&y1in[(e0 + r)*64 + cq*16 + 8];
            short4v h4, l4;
            #pragma unroll
            for (int half=0; half<2; ++half){
                const short8 y8 = half ? y8b : y8a;
                #pragma unroll
                for (int g=0; g<2; ++g){
                    #pragma unroll
                    for (int j=0;j<4;j++){
                        const int jj = g*4 + j;
                        const float a1 = fmaxf(fmaf(bf2fu((unsigned short)y8[jj]),
                                                    s1r[half*8+jj], h1r[half*8+jj]), 0.f);
                        const short hh = f2bf(a1);
                        h4[j] = hh;
                        l4[j] = f2bf(a1 - bf2f(hh));
                    }
                    const int c0 = cq*16 + half*8 + g*4;
                    *(short4v*)&AH[r*72 + c0] = h4;
                    *(short4v*)&AL[r*72 + c0] = l4;
                }
            }
        }
        __syncthreads();
        floatx4 acc2[8];
        #pragma unroll
        for (int nt=0;nt<8;nt++) acc2[nt] = (floatx4){0.f,0.f,0.f,0.f};
        #pragma unroll
        for (int ks=0; ks<2; ++ks){
            const int aoff = (m0 + L)*72 + ks*32 + Q*8;
            const short8 ah = *(const short8*)&AH[aoff];
            const short8 al = *(const short8*)&AL[aoff];
            #pragma unroll
            for (int nt=0;nt<8;nt++){
                const int boff = (nt*16+L)*72 + ks*32 + Q*8;
                const short8 wh = *(const short8*)&WH2[boff];
                const short8 wl = *(const short8*)&WL2[boff];
                acc2[nt] = __builtin_amdgcn_mfma_f32_16x16x32_bf16(ah, wh, acc2[nt], 0,0,0);
                acc2[nt] = __builtin_amdgcn_mfma_f32_16x16x32_bf16(ah, wl, acc2[nt], 0,0,0);
                acc2[nt] = __builtin_amdgcn_mfma_f32_16x16x32_bf16(al, wh, acc2[nt], 0,0,0);
            }
        }
        #pragma unroll
        for (int nt=0;nt<8;nt++){
            const int o = nt*16 + L;
            #pragma unroll
            for (int rr=0;rr<4;rr++){
                const float v = acc2[nt][rr];
                const int s = e0 + m0 + Q*4 + rr;
                y2out[s*128 + o] = (unsigned short)f2bf(v);
                sacc[nt] += v; qacc[nt] += v*v;
            }
        }
    }
    #pragma unroll
    for (int nt=0;nt<8;nt++){
        atomicAdd(&ssum[nt*16+L], sacc[nt]);
        atomicAdd(&ssq [nt*16+L], qacc[nt]);
    }
    __syncthreads();
    if (t < 128){
        atomicAdd(&bn2s[t], ssum[t]);
        atomicAdd(&bn2q[t], ssq[t]);
    }
}

// ------ combine (read bf16 Y2) ------
__global__ __launch_bounds__(256) void combine_fast_kernel(const unsigned short* y2, const float* attw,
        const float* sc2, const float* sh2, float* xcomb, float* msum){
    __shared__ float rs[512];
    const int t=threadIdx.x, w=t>>6, lane=t&63;
    const float s2a=sc2[lane], h2a=sh2[lane], s2b=sc2[64+lane], h2b=sh2[64+lane];
    const int pt0 = blockIdx.x*16 + w*4;
    const int hsel = lane >> 5;
    float m0=0.f, m1=0.f;
    for (int j=0;j<4;j++){
        const int pt = pt0 + j;
        float acc0=0.f, acc1=0.f;
        for (int k=0;k<K_;k++){
            const int s = pt*K_ + k;
            const float r0 = fmaxf(fmaf(bf2fu(y2[s*128+lane]),    s2a, h2a), 0.f);
            const float r1 = fmaxf(fmaf(bf2fu(y2[s*128+64+lane]), s2b, h2b), 0.f);
            acc0 = fmaf(r0, attw[s*4 + hsel],     acc0);
            acc1 = fmaf(r1, attw[s*4 + 2 + hsel], acc1);
        }
        xcomb[pt*128+lane]    = acc0;
        xcomb[pt*128+64+lane] = acc1;
        m0 += acc0; m1 += acc1;
    }
    rs[t]=m0; rs[256+t]=m1; __syncthreads();
    if (t<64){
        const int n = (blockIdx.x*16) >> 11;
        atomicAdd(&msum[n*128+t],    rs[t]+rs[t+64]+rs[t+128]+rs[t+192]);
        atomicAdd(&msum[n*128+64+t], rs[256+t]+rs[256+t+64]+rs[256+t+128]+rs[256+t+192]);
    }
}

// ------ SE gate ------
__global__ __launch_bounds__(128) void se_kernel(const float* msum, fpp w1se, fpp w2se, float* sev){
    __shared__ float tl[32];
    const int t = threadIdx.x;
    for (int n=0;n<N_;n++){
        if (t < 32){
            float acc=0.f;
            for (int c=0;c<128;c++) acc = fmaf(msum[n*128+c]*(1.f/2048.f), w1se[t*128+c], acc);
            tl[t] = fmaxf(acc, 0.f);
        }
        __syncthreads();
        float acc=0.f;
        for (int hh=0;hh<32;hh++) acc = fmaf(tl[hh], w2se[t*32+hh], acc);
        sev[n*128+t] = 1.f/(1.f+expf(-acc));
        __syncthreads();
    }
}

// ------ final: 256 blocks x 64 rows ------
__global__ __launch_bounds__(128) void final_kernel(fpp feat, fpp scw, const float* xcomb,
        const float* sev, const float* scsc, const float* shsc, float* out){
    __shared__ float swc[128*65];
    __shared__ float sf[64*64];
    const int t = threadIdx.x;
    for (int i=t;i<8192;i+=128) swc[(i>>6)*65+(i&63)] = scw[i];
    const int row0 = blockIdx.x*64;
    for (int i=t;i<4096;i+=128) sf[i] = feat[row0*64+i];
    __syncthreads();
    const int c = t;
    const float scl = scsc[c], shf = shsc[c];
    for (int r=0;r<64;r++){
        const int row = row0 + r;
        float acc = 0.f;
        #pragma unroll
        for (int k=0;k<64;k++) acc = fmaf(sf[r*64+k], swc[c*65+k], acc);
        const int n = row >> 11;
        out[row*128+c] = xcomb[row*128+c]*sev[n*128+c] + fmaxf(fmaf(acc, scl, shf), 0.f);
    }
}

extern "C" void kernel_launch(void* const* d_in, const int* in_sizes, int n_in,
                              void* d_out, int out_size, void* d_ws, size_t ws_size,
                              hipStream_t stream) {
    fpp points  = (fpp)d_in[0];
    fpp feat    = (fpp)d_in[1];
    fpp conv_w0 = (fpp)d_in[2];
    fpp conv_w1 = (fpp)d_in[3];
    fpp conv_w2 = (fpp)d_in[4];
    fpp bn_g0 = (fpp)d_in[5],  bn_b0 = (fpp)d_in[6];
    fpp bn_g1 = (fpp)d_in[7],  bn_b1 = (fpp)d_in[8];
    fpp bn_g2 = (fpp)d_in[9],  bn_b2 = (fpp)d_in[10];
    fpp attn_w1 = (fpp)d_in[11], attn_b1 = (fpp)d_in[12];
    fpp attn_w2 = (fpp)d_in[13], attn_b2 = (fpp)d_in[14];
    fpp tau  = (fpp)d_in[15];
    fpp sc_w = (fpp)d_in[16], sc_g = (fpp)d_in[17], sc_b = (fpp)d_in[18];
    fpp se_w1 = (fpp)d_in[19], se_w2 = (fpp)d_in[20];

    float* W = (float*)d_ws;
    float* BN0S=W+0;    float* BN0Q=W+64;
    float* BN1S=W+128;  float* BN1Q=W+192;
    float* BN2S=W+256;  float* BN2Q=W+384;
    float* SCS =W+512;  float* SCQ =W+640;
    float* SC0 =W+768;  float* SH0 =W+832;
    float* SC1 =W+896;  float* SH1 =W+960;
    float* SC2 =W+1024; float* SH2 =W+1152;
    float* SCSC=W+1280; float* SHSC=W+1408;
    float* MSUM=W+1536; float* SEV =W+2560;
    int*   IDX  = (int*)(W + 4096);
    float* U    = W + 266240;
    float* V    = U + 1048576;
    float* AU   = V + 1048576;
    float* AV   = AU + 524288;
    float* ATTW = AV + 524288;
    float* XCOMB= ATTW + 1048576;                          // ends 6,557,696 floats
    unsigned short* Y2 = (unsigned short*)(W + 6557696);   // 33,554,432 ushort
    unsigned short* Y1 = Y2 + 33554432;                    // 16,777,216 ushort

    hipMemsetAsync(d_ws, 0, 4096*sizeof(float), stream);

    knn_kernel<<<2048, 512, 0, stream>>>(points, IDX);
    feat_gemm_kernel<<<1024, 192, 0, stream>>>(feat, conv_w0, attn_w1, U, V, AU, AV);
    sc_stats_kernel<<<256, 128, 0, stream>>>(feat, sc_w, SCS, SCQ);
    attn_bn0_kernel<<<512, 256, 0, stream>>>(IDX, U, V, AU, AV,
                                             attn_b1, attn_w2, attn_b2, tau,
                                             ATTW, BN0S, BN0Q);
    bn_finalize2_kernel<<<1, 192, 0, stream>>>(BN0S, BN0Q, bn_g0, bn_b0,
                                               SCS, SCQ, sc_g, sc_b,
                                               SC0, SH0, SCSC, SHSC);
    mfma_conv1_kernel<<<512, 256, 0, stream>>>(IDX, U, V, conv_w1, SC0, SH0,
                                               BN1S, BN1Q, Y1);
    bn_finalize_kernel<<<1, 128, 0, stream>>>(BN1S, BN1Q, bn_g1, bn_b1,
                                              1.0f/262144.0f, 64, SC1, SH1);
    mfma_conv2_kernel<<<512, 256, 0, stream>>>(Y1, conv_w2, SC1, SH1,
                                               BN2S, BN2Q, Y2);
    bn_finalize_kernel<<<1, 128, 0, stream>>>(BN2S, BN2Q, bn_g2, bn_b2,
                                              1.0f/262144.0f, 128, SC2, SH2);
    combine_fast_kernel<<<1024, 256, 0, stream>>>(Y2, ATTW, SC2, SH2, XCOMB, MSUM);
    se_kernel<<<1, 128, 0, stream>>>(MSUM, se_w1, se_w2, SEV);
    final_kernel<<<256, 128, 0, stream>>>(feat, sc_w, XCOMB, SEV, SCSC, SHSC,
                                          (float*)d_out);
}